// Round 5
// baseline (399.407 us; speedup 1.0000x reference)
//
#include <hip/hip_runtime.h>

#define BB      8192
#define KK      50
#define NGLOB   16384
#define INV_T   0.5f
// TEMP^2 / B
#define OUTSCALE (4.0f / 8192.0f)

// Scatter batch_indices into the (memset-to--1) g2l table; also zero d_out.
__global__ __launch_bounds__(256) void g2l_fill_kernel(int* __restrict__ g2l,
                                                       const int* __restrict__ bidx,
                                                       int n, int cap,
                                                       float* __restrict__ out,
                                                       int out_n) {
    int i = blockIdx.x * 256 + threadIdx.x;
    if (i < out_n) out[i] = 0.0f;
    if (i < n) {
        int g = bidx[i];
        if (g >= 0 && g < cap) g2l[g] = i;   // JAX drops OOB scatter updates
    }
}

__global__ __launch_bounds__(256) void distill_loss_kernel(
        const float* __restrict__ logits,
        const int*   __restrict__ tidx,
        const float* __restrict__ tsc,
        const int*   __restrict__ g2l,
        int          g2l_cap,
        float*       __restrict__ out)
{
    __shared__ float wredm[4];        // cross-wave max reduce
    __shared__ float wreds[4];        // cross-wave sum reduce
    __shared__ int   locs[KK];        // wave-0-local dup detection

    const int row  = blockIdx.x;
    const int tid  = threadIdx.x;
    const int lane = tid & 63;
    const int wave = tid >> 6;

    // ---- issue the streaming row loads FIRST (8 x float4 = 32 B/lane) ----
    const float4* lrow = (const float4*)(logits + (size_t)row * BB);
    float4 v[8];
    #pragma unroll
    for (int c = 0; c < 8; ++c) v[c] = lrow[c * 256 + tid];

    // ---- sparse prefetch (wave 0 only; dependent chain overlaps the
    //      streaming loads + reductions below) ----
    int   myl = -1;
    float mys = 0.0f, xl = 0.0f, xdiag = 0.0f;
    if (tid < KK) {
        int g = tidx[row * KK + tid];
        mys = tsc[row * KK + tid];
        if ((unsigned)g < (unsigned)g2l_cap) myl = g2l[g];
        locs[tid] = myl;
        if (myl >= 0) xl = logits[(size_t)row * BB + myl];   // L1/L2 hit
    }
    if (tid == 0) xdiag = logits[(size_t)row * BB + row];

    // ---- row max ----
    float m = fmaxf(fmaxf(v[0].x, v[0].y), fmaxf(v[0].z, v[0].w));
    #pragma unroll
    for (int c = 1; c < 8; ++c)
        m = fmaxf(m, fmaxf(fmaxf(v[c].x, v[c].y), fmaxf(v[c].z, v[c].w)));
    #pragma unroll
    for (int off = 32; off >= 1; off >>= 1)
        m = fmaxf(m, __shfl_xor(m, off, 64));
    if (lane == 0) wredm[wave] = m;
    __syncthreads();
    m = fmaxf(fmaxf(wredm[0], wredm[1]), fmaxf(wredm[2], wredm[3]));

    // ---- sum exp((x - m) / T) ----
    float se = 0.0f;
    #pragma unroll
    for (int c = 0; c < 8; ++c) {
        se += __expf((v[c].x - m) * INV_T);
        se += __expf((v[c].y - m) * INV_T);
        se += __expf((v[c].z - m) * INV_T);
        se += __expf((v[c].w - m) * INV_T);
    }
    #pragma unroll
    for (int off = 32; off >= 1; off >>= 1)
        se += __shfl_xor(se, off, 64);
    if (lane == 0) wreds[wave] = se;
    __syncthreads();
    se = wreds[0] + wreds[1] + wreds[2] + wreds[3];
    const float logZ = m * INV_T + logf(se);

    // ---- sparse target epilogue (wave 0) ----
    if (wave == 0) {
        // last-wins dup semantics: drop entry if a LATER entry maps to the
        // same local; drop diag hits (overwritten by 1.0 in the reference);
        // drop zero scores (target>0 mask).
        bool kept = (myl >= 0) && (myl != row) && (mys > 0.0f);
        if (tid < KK && kept) {
            for (int kk = tid + 1; kk < KK; ++kk)
                if (locs[kk] == myl) { kept = false; break; }
        }
        float sS = kept ? mys : 0.0f;
        float sA = kept ? mys * __logf(mys) : 0.0f;           // r*log r
        float sC = kept ? mys * (xl * INV_T) : 0.0f;          // r*(x/T)
        if (lane == 0) sC += xdiag * INV_T;                   // diag: r=1
        #pragma unroll
        for (int off = 32; off >= 1; off >>= 1) {
            sS += __shfl_xor(sS, off, 64);
            sA += __shfl_xor(sA, off, 64);
            sC += __shfl_xor(sC, off, 64);
        }
        if (lane == 0) {
            float S = 1.0f + sS;                              // diag adds 1
            // loss_row = (A - C)/S + logZ - log S
            float rl = (sA - sC) / S + logZ - logf(S);
            atomicAdd(out, rl * OUTSCALE);
        }
    }
}

extern "C" void kernel_launch(void* const* d_in, const int* in_sizes, int n_in,
                              void* d_out, int out_size, void* d_ws, size_t ws_size,
                              hipStream_t stream) {
    const float* logits = (const float*)d_in[0];
    const int*   bidx   = (const int*)d_in[1];
    const int*   tidx   = (const int*)d_in[2];
    const float* tsc    = (const float*)d_in[3];
    float* out = (float*)d_out;
    int*   g2l = (int*)d_ws;

    const int Bn = in_sizes[1];       // 8192

    // Defensive clamp: never touch past the workspace.
    int cap = NGLOB;
    size_t need = (size_t)NGLOB * sizeof(int);
    if (ws_size < need) cap = (int)(ws_size / sizeof(int));

    if (cap > 0) {
        // 0xFF bytes == -1 per int: table init without a kernel launch
        hipMemsetAsync(g2l, 0xFF, (size_t)cap * sizeof(int), stream);
        g2l_fill_kernel<<<(Bn + 255) / 256, 256, 0, stream>>>(
            g2l, bidx, Bn, cap, out, out_size);
    }
    distill_loss_kernel<<<Bn, 256, 0, stream>>>(logits, tidx, tsc, g2l, cap, out);
}